// Round 1
// baseline (1171.761 us; speedup 1.0000x reference)
//
#include <hip/hip_runtime.h>
#include <math.h>

// Problem constants (from reference)
#define B_   16
#define C_   256
#define N_   16384      // H*W = 128*128
#define NH_  4
#define HD_  16
#define MEM_ 64
#define G_   8
#define CPG_ 32         // channels per group

// Workspace layout (float offsets)
#define OFF_SUM  0        // [B][C] per-channel sums of x
#define OFF_SQ   4096     // [B][C] per-channel sum of squares
#define OFF_S    8192     // [B][C] folded GN scale
#define OFF_T    12288    // [B][C] folded GN shift
#define OFF_M    16384    // [B][4][16][16] linear-attn state
#define OFF_Z    32768    // [B][64]
#define OFF_GATE 33792    // [B]
#define OFF_WT   33808    // [256][192] transposed Wk|Wv|Wq columns

// ---------------------------------------------------------------------------
// K1: per-(b,c) sum and sumsq over the 16384 pixels. One block per (b,c).
// ---------------------------------------------------------------------------
__global__ __launch_bounds__(256) void k_stats(const float* __restrict__ x,
                                               float* __restrict__ ws) {
    const int bc = blockIdx.x;                    // 0..4095
    const float4* p4 = (const float4*)(x + (size_t)bc * N_);
    float s = 0.f, q = 0.f;
    #pragma unroll 4
    for (int i = threadIdx.x; i < N_ / 4; i += 256) {
        float4 v = p4[i];
        s += v.x + v.y + v.z + v.w;
        q += v.x * v.x + v.y * v.y + v.z * v.z + v.w * v.w;
    }
    #pragma unroll
    for (int o = 32; o > 0; o >>= 1) {
        s += __shfl_down(s, o);
        q += __shfl_down(q, o);
    }
    __shared__ float ls[4], lq[4];
    const int wid = threadIdx.x >> 6, lane = threadIdx.x & 63;
    if (lane == 0) { ls[wid] = s; lq[wid] = q; }
    __syncthreads();
    if (threadIdx.x == 0) {
        ws[OFF_SUM + bc] = ls[0] + ls[1] + ls[2] + ls[3];
        ws[OFF_SQ  + bc] = lq[0] + lq[1] + lq[2] + lq[3];
    }
}

// ---------------------------------------------------------------------------
// K_tr: transpose Wk/Wv/Wq into [c][192] column layout for uniform s_loads.
// ---------------------------------------------------------------------------
__global__ void k_tr(const float* __restrict__ Wk, const float* __restrict__ Wv,
                     const float* __restrict__ Wq, float* __restrict__ ws) {
    const int c = blockIdx.x;      // 0..255
    const int t = threadIdx.x;     // 0..191
    float v;
    if (t < 64)       v = Wk[t * C_ + c];
    else if (t < 128) v = Wv[(t - 64) * C_ + c];
    else              v = Wq[(t - 128) * C_ + c];
    ws[OFF_WT + c * 192 + t] = v;
}

// ---------------------------------------------------------------------------
// K2: per-batch prep — GN fold (s,t), gate MLP, init M=M0 / Z=Z0.
// One block per batch.
// ---------------------------------------------------------------------------
__global__ __launch_bounds__(256) void k_prep(
        const float* __restrict__ gnw, const float* __restrict__ gnb,
        const float* __restrict__ M0,  const float* __restrict__ Z0,
        const float* __restrict__ g1w, const float* __restrict__ g1b,
        const float* __restrict__ g2w, const float* __restrict__ g2b,
        float* __restrict__ ws, float* __restrict__ out_gate) {
    const int b = blockIdx.x, t = threadIdx.x;
    __shared__ float mu[G_], rs[G_];
    __shared__ float pooled[C_];
    __shared__ float hidden[64];

    if (t < G_) {
        float S = 0.f, Q = 0.f;
        for (int c = t * CPG_; c < (t + 1) * CPG_; ++c) {
            S += ws[OFF_SUM + b * C_ + c];
            Q += ws[OFF_SQ  + b * C_ + c];
        }
        const float cnt = (float)(CPG_ * N_);
        const float m = S / cnt;
        const float var = Q / cnt - m * m;
        mu[t] = m;
        rs[t] = rsqrtf(var + 1e-5f);
    }
    __syncthreads();
    {   // fold GN into per-channel affine; pooled mean of x_norm
        const int c = t;
        const int g = c / CPG_;
        const float sc = rs[g] * gnw[c];
        const float tc = gnb[c] - mu[g] * sc;
        ws[OFF_S + b * C_ + c] = sc;
        ws[OFF_T + b * C_ + c] = tc;
        const float meanc = ws[OFF_SUM + b * C_ + c] * (1.f / (float)N_);
        pooled[c] = meanc * sc + tc;
    }
    __syncthreads();
    if (t < 64) {
        float a = g1b[t];
        for (int c = 0; c < C_; ++c) a = fmaf(pooled[c], g1w[t * C_ + c], a);
        hidden[t] = 0.5f * a * (1.f + erff(a * 0.70710678118654752f));  // exact GELU
    }
    __syncthreads();
    if (t == 0) {
        float z = g2b[0];
        for (int j = 0; j < 64; ++j) z = fmaf(hidden[j], g2w[j], z);
        const float gate = 1.f / (1.f + expf(-z));
        ws[OFF_GATE + b] = gate;
        out_gate[b] = gate;                         // second output of the tuple
    }
    // init attention state with warm start
    for (int i = t; i < NH_ * HD_ * HD_; i += 256) ws[OFF_M + b * 1024 + i] = M0[i];
    for (int i = t; i < NH_ * HD_;       i += 256) ws[OFF_Z + b * 64 + i]   = Z0[i];
}

// ---------------------------------------------------------------------------
// K3: compute phi_k, v per pixel; block-reduce outer products into M, Z.
// One thread per pixel; 256 pixels per block. Weights via uniform scalar loads.
// ---------------------------------------------------------------------------
__global__ __launch_bounds__(256, 2) void k_mz(const float* __restrict__ x,
                                               float* __restrict__ ws) {
    const int b = blockIdx.y;
    const int t = threadIdx.x;
    const int pix = blockIdx.x * 256 + t;
    const float* __restrict__ xb = x + (size_t)b * C_ * N_ + pix;
    const float* __restrict__ wt = ws + OFF_WT;
    const float* __restrict__ sv = ws + OFF_S + b * C_;
    const float* __restrict__ tv = ws + OFF_T + b * C_;

    float kacc[64], vacc[64];
    #pragma unroll
    for (int d = 0; d < 64; ++d) { kacc[d] = 0.f; vacc[d] = 0.f; }

    for (int c = 0; c < C_; ++c) {
        float xv = xb[(size_t)c * N_];
        xv = fmaf(xv, sv[c], tv[c]);          // folded GroupNorm
        const float* __restrict__ w = wt + c * 192;
        #pragma unroll
        for (int d = 0; d < 64; ++d) {
            kacc[d] = fmaf(w[d],      xv, kacc[d]);
            vacc[d] = fmaf(w[64 + d], xv, vacc[d]);
        }
    }
    // phi_k = elu(k)+1
    #pragma unroll
    for (int d = 0; d < 64; ++d)
        kacc[d] = kacc[d] > 0.f ? kacc[d] + 1.f : __expf(kacc[d]);

    // block outer-product reduction, one head at a time (padded LDS: stride 17)
    __shared__ float phs[256 * 17];
    __shared__ float vls[256 * 17];
    const int d_ = t & 15, e_ = t >> 4;       // 16 x 16 output assignment

    #pragma unroll
    for (int h = 0; h < NH_; ++h) {
        __syncthreads();
        #pragma unroll
        for (int i = 0; i < 16; ++i) {
            phs[t * 17 + i] = kacc[h * 16 + i];
            vls[t * 17 + i] = vacc[h * 16 + i];
        }
        __syncthreads();
        float m = 0.f, z = 0.f;
        #pragma unroll 4
        for (int p = 0; p < 256; ++p) {
            const float ph = phs[p * 17 + d_];
            const float vv = vls[p * 17 + e_];
            m = fmaf(ph, vv, m);
            if (e_ == 0) z += ph;
        }
        atomicAdd(&ws[OFF_M + b * 1024 + h * 256 + d_ * 16 + e_], m);
        if (e_ == 0) atomicAdd(&ws[OFF_Z + b * 64 + h * 16 + d_], z);
    }
}

// ---------------------------------------------------------------------------
// K4: recompute phi_q per pixel, apply M/Z, project with Wo, gated residual.
// ---------------------------------------------------------------------------
__global__ __launch_bounds__(256, 2) void k_out(const float* __restrict__ x,
                                                const float* __restrict__ Wo,
                                                const float* __restrict__ bo,
                                                float* __restrict__ out,
                                                const float* __restrict__ ws) {
    const int b = blockIdx.y;
    const int pix = blockIdx.x * 256 + threadIdx.x;
    const float* __restrict__ xb = x + (size_t)b * C_ * N_ + pix;
    const float* __restrict__ wt = ws + OFF_WT;
    const float* __restrict__ sv = ws + OFF_S + b * C_;
    const float* __restrict__ tv = ws + OFF_T + b * C_;

    float qacc[64];
    #pragma unroll
    for (int d = 0; d < 64; ++d) qacc[d] = 0.f;

    for (int c = 0; c < C_; ++c) {
        float xv = xb[(size_t)c * N_];
        xv = fmaf(xv, sv[c], tv[c]);
        const float* __restrict__ w = wt + c * 192 + 128;   // Wq columns
        #pragma unroll
        for (int d = 0; d < 64; ++d) qacc[d] = fmaf(w[d], xv, qacc[d]);
    }
    #pragma unroll
    for (int d = 0; d < 64; ++d)
        qacc[d] = qacc[d] > 0.f ? qacc[d] + 1.f : __expf(qacc[d]);   // phi_q

    const float* __restrict__ Mb = ws + OFF_M + b * 1024;
    const float* __restrict__ Zb = ws + OFF_Z + b * 64;
    float y[64];
    #pragma unroll
    for (int e = 0; e < 64; ++e) y[e] = 0.f;
    float den[NH_] = {0.f, 0.f, 0.f, 0.f};

    #pragma unroll
    for (int h = 0; h < NH_; ++h) {
        #pragma unroll
        for (int d = 0; d < 16; ++d) {
            const float qv = qacc[h * 16 + d];
            den[h] = fmaf(Zb[h * 16 + d], qv, den[h]);
            const float* __restrict__ Mr = Mb + h * 256 + d * 16;  // uniform (scalar) loads
            #pragma unroll
            for (int e = 0; e < 16; ++e)
                y[h * 16 + e] = fmaf(Mr[e], qv, y[h * 16 + e]);
        }
    }
    #pragma unroll
    for (int h = 0; h < NH_; ++h) {
        const float dn = den[h] > 1e-4f ? den[h] : 1e-4f;
        const float r = 1.f / dn;
        #pragma unroll
        for (int e = 0; e < 16; ++e) y[h * 16 + e] *= r;
    }

    const float gate = ws[OFF_GATE + b];
    float* __restrict__ ob = out + (size_t)b * C_ * N_ + pix;
    for (int c = 0; c < C_; ++c) {
        float acc = bo[c];
        const float* __restrict__ wo = Wo + c * 64;          // uniform row
        #pragma unroll
        for (int e = 0; e < 64; ++e) acc = fmaf(wo[e], y[e], acc);
        ob[(size_t)c * N_] = fmaf(gate, acc, xb[(size_t)c * N_]);
    }
}

// ---------------------------------------------------------------------------
extern "C" void kernel_launch(void* const* d_in, const int* in_sizes, int n_in,
                              void* d_out, int out_size, void* d_ws, size_t ws_size,
                              hipStream_t stream) {
    const float* x   = (const float*)d_in[0];
    const float* gnw = (const float*)d_in[1];
    const float* gnb = (const float*)d_in[2];
    const float* Wk  = (const float*)d_in[3];
    const float* Wv  = (const float*)d_in[4];
    const float* Wq  = (const float*)d_in[5];
    const float* Wo  = (const float*)d_in[6];
    const float* bo  = (const float*)d_in[7];
    const float* M0  = (const float*)d_in[8];
    const float* Z0  = (const float*)d_in[9];
    const float* g1w = (const float*)d_in[10];
    const float* g1b = (const float*)d_in[11];
    const float* g2w = (const float*)d_in[12];
    const float* g2b = (const float*)d_in[13];
    float* out = (float*)d_out;
    float* ws  = (float*)d_ws;

    hipLaunchKernelGGL(k_stats, dim3(B_ * C_), dim3(256), 0, stream, x, ws);
    hipLaunchKernelGGL(k_tr,    dim3(C_),      dim3(192), 0, stream, Wk, Wv, Wq, ws);
    hipLaunchKernelGGL(k_prep,  dim3(B_),      dim3(256), 0, stream,
                       gnw, gnb, M0, Z0, g1w, g1b, g2w, g2b, ws,
                       out + (size_t)B_ * C_ * N_);
    hipLaunchKernelGGL(k_mz,    dim3(N_ / 256, B_), dim3(256), 0, stream, x, ws);
    hipLaunchKernelGGL(k_out,   dim3(N_ / 256, B_), dim3(256), 0, stream,
                       x, Wo, bo, out, ws);
}